// Round 6
// baseline (595.159 us; speedup 1.0000x reference)
//
#include <hip/hip_runtime.h>
#include <math.h>

#define N_NODES 100000
#define N_EDGES 3200000
#define NPB 256                               // nodes per bucket (dst & 255, dst >> 8)
#define NB  ((N_NODES + NPB - 1) / NPB)       // 391 buckets
#define PART_B 512                            // partition blocks
#define CPB (N_EDGES / PART_B)                // 6250 edges per partition block (exact)

typedef unsigned long long u64;
typedef unsigned int u32;

// ---------------- bucket-partition build (NO global atomics) ----------------

// per-block histogram matrix: hist_mat[blk][bin]
__global__ void hist_k(const int* __restrict__ dst, int* __restrict__ hist_mat) {
    __shared__ int h[NB];
    for (int t = threadIdx.x; t < NB; t += blockDim.x) h[t] = 0;
    __syncthreads();
    int base = blockIdx.x * CPB;
    for (int it = 0; it < (CPB + 255) / 256; it++) {
        int e = base + it * 256 + threadIdx.x;
        if (e < base + CPB) atomicAdd(&h[dst[e] >> 8], 1);   // LDS atomic only
    }
    __syncthreads();
    for (int t = threadIdx.x; t < NB; t += blockDim.x)
        hist_mat[blockIdx.x * NB + t] = h[t];
}

// column-wise exclusive scan over partition blocks: one block per bin
__global__ void colscan_k(int* __restrict__ hist_mat, int* __restrict__ tot) {
    __shared__ int s[PART_B];
    int bin = blockIdx.x, t = threadIdx.x;
    int v = hist_mat[t * NB + bin];
    s[t] = v;
    __syncthreads();
#pragma unroll
    for (int off = 1; off < PART_B; off <<= 1) {
        int u = (t >= off) ? s[t - off] : 0;
        __syncthreads();
        s[t] += u;
        __syncthreads();
    }
    hist_mat[t * NB + bin] = s[t] - v;        // exclusive within column
    if (t == PART_B - 1) tot[bin] = s[t];
}

// exclusive scan of bucket totals -> bucket bases
__global__ void base_k(const int* __restrict__ tot, int* __restrict__ bbase) {
    __shared__ int s[512];
    int t = threadIdx.x;
    int v = (t < NB) ? tot[t] : 0;
    s[t] = v;
    __syncthreads();
#pragma unroll
    for (int off = 1; off < 512; off <<= 1) {
        int u = (t >= off) ? s[t - off] : 0;
        __syncthreads();
        s[t] += u;
        __syncthreads();
    }
    if (t < NB) bbase[t] = s[t] - v;
    if (t == 0) bbase[NB] = N_EDGES;
}

// scatter edges to bucket-grouped ebuf: packed (src<<8 | dstLow, w)
__global__ void part_k(const int* __restrict__ src, const int* __restrict__ dst,
                       const float* __restrict__ w, const int* __restrict__ hist_mat,
                       const int* __restrict__ bbase, u64* __restrict__ ebuf) {
    __shared__ int cur[NB];
    for (int t = threadIdx.x; t < NB; t += blockDim.x)
        cur[t] = bbase[t] + hist_mat[blockIdx.x * NB + t];
    __syncthreads();
    int base = blockIdx.x * CPB;
    for (int it = 0; it < (CPB + 255) / 256; it++) {
        int e = base + it * 256 + threadIdx.x;
        if (e < base + CPB) {
            int d = dst[e];
            int p = atomicAdd(&cur[d >> 8], 1);             // LDS atomic only
            u32 hi = ((u32)src[e] << 8) | (u32)(d & 255);
            ebuf[p] = ((u64)hi << 32) | (u64)__float_as_uint(w[e]);
        }
    }
}

// weighted degree per bucket via LDS float accumulate -> dinv = rsqrt(1 + sum w)
__global__ void deg_k(const u64* __restrict__ ebuf, const int* __restrict__ bbase,
                      float* __restrict__ dinv) {
    __shared__ float sdeg[NPB];
    int b = blockIdx.x;
    for (int t = threadIdx.x; t < NPB; t += blockDim.x) sdeg[t] = 0.0f;
    __syncthreads();
    int j0 = bbase[b], j1 = bbase[b + 1];
    for (int j = j0 + threadIdx.x; j < j1; j += blockDim.x) {
        u64 pe = ebuf[j];
        atomicAdd(&sdeg[(u32)(pe >> 32) & 255], __uint_as_float((u32)pe));
    }
    __syncthreads();
    int node = b * NPB + threadIdx.x;
    if (threadIdx.x < NPB && node < N_NODES)
        dinv[node] = rsqrtf(1.0f + sdeg[threadIdx.x]);
}

// ---------------- dense / gather kernels ----------------

// g1 = (x @ W1) * dinv[node]
__global__ void gemm1(const float* __restrict__ x, const float* __restrict__ W1,
                      const float* __restrict__ dinv, float* __restrict__ g1) {
    __shared__ float sW[64 * 16];
    for (int t = threadIdx.x; t < 64 * 16; t += blockDim.x) sW[t] = W1[t];
    __syncthreads();
    int gid = blockIdx.x * blockDim.x + threadIdx.x;
    int node = gid >> 4, c = gid & 15;
    if (node >= N_NODES) return;
    const float* xr = x + node * 64;
    float acc = 0.0f;
#pragma unroll
    for (int k = 0; k < 64; k++) acc += xr[k] * sW[k * 16 + c];
    g1[node * 16 + c] = acc * dinv[node];
}

// conv1 aggregate per bucket in LDS, fused bias+relu+gemm2 epilogue -> y2 = x2pre*dinv
__global__ void __launch_bounds__(512) gather1_k(
        const u64* __restrict__ ebuf, const int* __restrict__ bbase,
        const float* __restrict__ dinv, const float* __restrict__ g1,
        const float* __restrict__ b1, const float* __restrict__ W2,
        float* __restrict__ y2) {
    __shared__ float sacc[NPB * 16];          // 16 KB
    int b = blockIdx.x;
    for (int t = threadIdx.x; t < NPB * 16; t += blockDim.x) sacc[t] = 0.0f;
    __syncthreads();
    int j0 = bbase[b], j1 = bbase[b + 1];
    int c = threadIdx.x & 15;
    // 32 edges per iteration, 16 lanes per edge (one per feature)
    for (int j = j0 + (threadIdx.x >> 4); j < j1; j += 32) {
        u64 pe = ebuf[j];
        u32 hi = (u32)(pe >> 32);
        int s = (int)(hi >> 8);
        int lo = (int)(hi & 255);
        float wr = __uint_as_float((u32)pe);
        atomicAdd(&sacc[lo * 16 + c], g1[s * 16 + c] * wr);   // LDS atomic
    }
    __syncthreads();
    // epilogue: 32 nodes per iteration
    for (int nb = (threadIdx.x >> 4); nb < NPB; nb += 32) {
        int node = b * NPB + nb;
        if (node < N_NODES) {
            float di = dinv[node];
            float acc = sacc[nb * 16 + c] + g1[node * 16 + c];   // + self-loop
            float v = acc * di + b1[c];
            v = v > 0.0f ? v : 0.0f;                             // h2 in-register
            float p0 = v * W2[c * 2];
            float p1 = v * W2[c * 2 + 1];
#pragma unroll
            for (int off = 8; off >= 1; off >>= 1) {
                p0 += __shfl_xor(p0, off, 16);
                p1 += __shfl_xor(p1, off, 16);
            }
            if (c == 0) {
                y2[node * 2]     = p0 * di;                      // pre-scale for layer 2
                y2[node * 2 + 1] = p1 * di;
            }
        }
    }
}

// conv2 aggregate per bucket in LDS + bias + relu + sigmoid head
__global__ void gather2_k(const u64* __restrict__ ebuf, const int* __restrict__ bbase,
                          const float* __restrict__ dinv, const float* __restrict__ y2,
                          const float* __restrict__ b2, const float* __restrict__ lin_w,
                          const float* __restrict__ lin_b, float* __restrict__ out) {
    __shared__ float sacc[NPB * 2];
    int b = blockIdx.x;
    for (int t = threadIdx.x; t < NPB * 2; t += blockDim.x) sacc[t] = 0.0f;
    __syncthreads();
    int j0 = bbase[b], j1 = bbase[b + 1];
    int k = threadIdx.x & 1;
    // 128 edges per iteration, 2 lanes per edge
    for (int j = j0 + (threadIdx.x >> 1); j < j1; j += 128) {
        u64 pe = ebuf[j];
        u32 hi = (u32)(pe >> 32);
        int s = (int)(hi >> 8);
        int lo = (int)(hi & 255);
        float wr = __uint_as_float((u32)pe);
        atomicAdd(&sacc[lo * 2 + k], y2[s * 2 + k] * wr);      // LDS atomic
    }
    __syncthreads();
    int node = b * NPB + threadIdx.x;
    if (threadIdx.x < NPB && node < N_NODES) {
        float di = dinv[node];
        float x20 = (sacc[threadIdx.x * 2]     + y2[node * 2])     * di + b2[0];
        float x21 = (sacc[threadIdx.x * 2 + 1] + y2[node * 2 + 1]) * di + b2[1];
        out[N_NODES + node * 2]     = x20;
        out[N_NODES + node * 2 + 1] = x21;
        float r0 = x20 > 0.0f ? x20 : 0.0f;
        float r1 = x21 > 0.0f ? x21 : 0.0f;
        float z = r0 * lin_w[0] + r1 * lin_w[1] + lin_b[0];
        out[node] = 1.0f / (1.0f + expf(-z));
    }
}

extern "C" void kernel_launch(void* const* d_in, const int* in_sizes, int n_in,
                              void* d_out, int out_size, void* d_ws, size_t ws_size,
                              hipStream_t stream) {
    const float* x     = (const float*)d_in[0];
    const int*   ei    = (const int*)d_in[1];   // [2, E] flattened
    const float* ew    = (const float*)d_in[2];
    const float* W1    = (const float*)d_in[3];
    const float* b1    = (const float*)d_in[4];
    const float* W2    = (const float*)d_in[5];
    const float* b2    = (const float*)d_in[6];
    const float* lin_w = (const float*)d_in[7];
    const float* lin_b = (const float*)d_in[8];
    float* out = (float*)d_out;

    const int* src = ei;
    const int* dst = ei + N_EDGES;

    // ---- workspace carve-up ----
    char* w8 = (char*)d_ws;
    size_t off = 0;
    auto take = [&](size_t bytes) { char* p = w8 + off; off += (bytes + 15) & ~((size_t)15); return (void*)p; };
    int*   hist_mat = (int*)  take((size_t)PART_B * NB * 4);   // ~800 KB
    int*   tot      = (int*)  take((size_t)NB * 4);
    int*   bbase    = (int*)  take((size_t)(NB + 1) * 4);
    u64*   ebuf     = (u64*)  take((size_t)N_EDGES * 8);       // 25.6 MB
    float* dinv     = (float*)take((size_t)N_NODES * 4);
    float* g1       = (float*)take((size_t)N_NODES * 16 * 4);  // 6.4 MB
    float* y2       = (float*)take((size_t)N_NODES * 2 * 4);

    const int B = 256;

    // bucket partition (zero global atomics, no memsets needed)
    hist_k<<<PART_B, B, 0, stream>>>(dst, hist_mat);
    colscan_k<<<NB, PART_B, 0, stream>>>(hist_mat, tot);
    base_k<<<1, 512, 0, stream>>>(tot, bbase);
    part_k<<<PART_B, B, 0, stream>>>(src, dst, ew, hist_mat, bbase, ebuf);

    // degree / norm factor
    deg_k<<<NB, B, 0, stream>>>(ebuf, bbase, dinv);

    // layer 1 (norm algebraically folded: g1 pre-scaled by dinv[src])
    gemm1<<<(16 * N_NODES + B - 1) / B, B, 0, stream>>>(x, W1, dinv, g1);
    gather1_k<<<NB, 512, 0, stream>>>(ebuf, bbase, dinv, g1, b1, W2, y2);

    // layer 2 + head
    gather2_k<<<NB, B, 0, stream>>>(ebuf, bbase, dinv, y2, b2, lin_w, lin_b, out);
}

// Round 8
// 337.758 us; speedup vs baseline: 1.7621x; 1.7621x over previous
//
#include <hip/hip_runtime.h>
#include <math.h>

#define N_NODES 100000
#define N_EDGES 3200000
#define NPB 256                               // nodes per bucket (dst & 255, dst >> 8)
#define NB  ((N_NODES + NPB - 1) / NPB)       // 391 buckets
#define PART_B 512                            // partition blocks
#define CPB (N_EDGES / PART_B)                // 6250 edges per partition block (exact)

typedef unsigned long long u64;
typedef unsigned int u32;

// ---------------- stage 1: multisplit into 391 buckets (NO global atomics) ----------

// per-block histogram matrix: hist_mat[blk][bin]
__global__ void hist_k(const int* __restrict__ dst, int* __restrict__ hist_mat) {
    __shared__ int h[NB];
    for (int t = threadIdx.x; t < NB; t += blockDim.x) h[t] = 0;
    __syncthreads();
    int base = blockIdx.x * CPB;
    for (int it = 0; it < (CPB + 255) / 256; it++) {
        int e = base + it * 256 + threadIdx.x;
        if (e < base + CPB) atomicAdd(&h[dst[e] >> 8], 1);   // LDS atomic only
    }
    __syncthreads();
    for (int t = threadIdx.x; t < NB; t += blockDim.x)
        hist_mat[blockIdx.x * NB + t] = h[t];
}

// column-wise exclusive scan over partition blocks: one block per bin
__global__ void colscan_k(int* __restrict__ hist_mat, int* __restrict__ tot) {
    __shared__ int s[PART_B];
    int bin = blockIdx.x, t = threadIdx.x;
    int v = hist_mat[t * NB + bin];
    s[t] = v;
    __syncthreads();
#pragma unroll
    for (int off = 1; off < PART_B; off <<= 1) {
        int u = (t >= off) ? s[t - off] : 0;
        __syncthreads();
        s[t] += u;
        __syncthreads();
    }
    hist_mat[t * NB + bin] = s[t] - v;        // exclusive within column
    if (t == PART_B - 1) tot[bin] = s[t];
}

// exclusive scan of bucket totals -> bucket bases
__global__ void base_k(const int* __restrict__ tot, int* __restrict__ bbase) {
    __shared__ int s[512];
    int t = threadIdx.x;
    int v = (t < NB) ? tot[t] : 0;
    s[t] = v;
    __syncthreads();
#pragma unroll
    for (int off = 1; off < 512; off <<= 1) {
        int u = (t >= off) ? s[t - off] : 0;
        __syncthreads();
        s[t] += u;
        __syncthreads();
    }
    if (t < NB) bbase[t] = s[t] - v;
    if (t == 0) bbase[NB] = N_EDGES;
}

// scatter edges to bucket-grouped ebuf: packed (src<<8 | dstLow, w); ~16-edge runs
__global__ void part_k(const int* __restrict__ src, const int* __restrict__ dst,
                       const float* __restrict__ w, const int* __restrict__ hist_mat,
                       const int* __restrict__ bbase, u64* __restrict__ ebuf) {
    __shared__ int cur[NB];
    for (int t = threadIdx.x; t < NB; t += blockDim.x)
        cur[t] = bbase[t] + hist_mat[blockIdx.x * NB + t];
    __syncthreads();
    int base = blockIdx.x * CPB;
    for (int it = 0; it < (CPB + 255) / 256; it++) {
        int e = base + it * 256 + threadIdx.x;
        if (e < base + CPB) {
            int d = dst[e];
            int p = atomicAdd(&cur[d >> 8], 1);             // LDS atomic only
            u32 hi = ((u32)src[e] << 8) | (u32)(d & 255);
            ebuf[p] = ((u64)hi << 32) | (u64)__float_as_uint(w[e]);
        }
    }
}

// ---------------- stage 2: per-bucket CSR-ization + degree (one block per bucket) ----
__global__ void __launch_bounds__(512) csr_deg_k(
        const u64* __restrict__ ebuf, const int* __restrict__ bbase,
        int* __restrict__ row_ptr, float* __restrict__ dinv,
        u64* __restrict__ pedge) {
    __shared__ int   cnt[NPB];
    __shared__ float wsum[NPB];
    __shared__ int   sc[NPB];
    __shared__ int   cur[NPB];
    int b = blockIdx.x, t = threadIdx.x;
    if (t < NPB) { cnt[t] = 0; wsum[t] = 0.0f; }
    __syncthreads();
    int j0 = bbase[b], j1 = bbase[b + 1];
    for (int j = j0 + t; j < j1; j += 512) {
        u64 pe = ebuf[j];
        int lo = (int)((u32)(pe >> 32) & 255);
        atomicAdd(&cnt[lo], 1);                              // LDS atomic
        atomicAdd(&wsum[lo], __uint_as_float((u32)pe));      // LDS atomic
    }
    __syncthreads();
    // exclusive scan of cnt[0..255] (Hillis-Steele; all 512 threads hit barriers)
    int v = (t < NPB) ? cnt[t] : 0;
    if (t < NPB) sc[t] = v;
    __syncthreads();
#pragma unroll
    for (int off = 1; off < NPB; off <<= 1) {
        int u = (t < NPB && t >= off) ? sc[t - off] : 0;
        __syncthreads();
        if (t < NPB) sc[t] += u;
        __syncthreads();
    }
    int node = b * NPB + t;
    if (t < NPB) {
        int excl = sc[t] - v;
        cur[t] = j0 + excl;
        if (node < N_NODES) {
            row_ptr[node] = j0 + excl;
            dinv[node] = rsqrtf(1.0f + wsum[t]);             // self-loop weight 1
        }
    }
    if (b == NB - 1 && t == 0) row_ptr[N_NODES] = N_EDGES;
    __syncthreads();
    // pass 2: node-grouped scatter within the bucket's contiguous range
    for (int j = j0 + t; j < j1; j += 512) {
        u64 pe = ebuf[j];
        u32 hi = (u32)(pe >> 32);
        int lo = (int)(hi & 255);
        int p = atomicAdd(&cur[lo], 1);                      // LDS atomic
        pedge[p] = ((u64)(hi >> 8) << 32) | (u64)(u32)pe;    // (src, raw w)
    }
}

// ---------------- dense / gather kernels (round-5 proven structure) ----------------

// g1 = (x @ W1) * dinv[node]   (pre-scaled by source-side norm factor)
__global__ void gemm1(const float* __restrict__ x, const float* __restrict__ W1,
                      const float* __restrict__ dinv, float* __restrict__ g1) {
    __shared__ float sW[64 * 16];
    for (int t = threadIdx.x; t < 64 * 16; t += blockDim.x) sW[t] = W1[t];
    __syncthreads();
    int gid = blockIdx.x * blockDim.x + threadIdx.x;
    int node = gid >> 4, c = gid & 15;
    if (node >= N_NODES) return;
    const float* xr = x + node * 64;
    float acc = 0.0f;
#pragma unroll
    for (int k = 0; k < 64; k++) acc += xr[k] * sW[k * 16 + c];
    g1[node * 16 + c] = acc * dinv[node];
}

// conv1 gather + bias + relu, fused gemm2; emits y2 = x2pre * dinv (pre-scaled)
__global__ void gather1(const int* __restrict__ row_ptr, const u64* __restrict__ pedge,
                        const float* __restrict__ dinv, const float* __restrict__ g1,
                        const float* __restrict__ b1, const float* __restrict__ W2,
                        float* __restrict__ y2) {
    int gid = blockIdx.x * blockDim.x + threadIdx.x;
    int node = gid >> 4, c = gid & 15;
    if (node >= N_NODES) return;
    float acc = g1[node * 16 + c];                     // self-loop (g1 = h1*dinv)
    int j0 = row_ptr[node], j1 = row_ptr[node + 1];
    for (int j = j0; j < j1; j++) {
        u64 pe = pedge[j];
        int s = (int)(pe >> 32);
        float wr = __uint_as_float((unsigned)pe);
        acc += g1[s * 16 + c] * wr;
    }
    float di = dinv[node];
    float v = acc * di + b1[c];
    v = v > 0.0f ? v : 0.0f;                           // h2, in-register
    // fused gemm2: x2pre[node][k] = sum_c v_c * W2[c][k]
    float p0 = v * W2[c * 2];
    float p1 = v * W2[c * 2 + 1];
#pragma unroll
    for (int off = 8; off >= 1; off >>= 1) {
        p0 += __shfl_xor(p0, off, 16);
        p1 += __shfl_xor(p1, off, 16);
    }
    if (c == 0) {
        y2[node * 2]     = p0 * di;                    // pre-scale for layer 2
        y2[node * 2 + 1] = p1 * di;
    }
}

// conv2 gather (8 lanes/node) + bias + relu + sigmoid head
__global__ void gather2(const int* __restrict__ row_ptr, const u64* __restrict__ pedge,
                        const float* __restrict__ dinv, const float* __restrict__ y2,
                        const float* __restrict__ b2, const float* __restrict__ lin_w,
                        const float* __restrict__ lin_b, float* __restrict__ out) {
    int gid = blockIdx.x * blockDim.x + threadIdx.x;
    int i = gid >> 3, l = gid & 7;
    if (i >= N_NODES) return;
    int j0 = row_ptr[i], j1 = row_ptr[i + 1];
    float a0 = 0.0f, a1 = 0.0f;
    for (int j = j0 + l; j < j1; j += 8) {
        u64 pe = pedge[j];
        int s = (int)(pe >> 32);
        float wr = __uint_as_float((unsigned)pe);
        const float2 ys = *(const float2*)(y2 + s * 2);
        a0 += ys.x * wr;
        a1 += ys.y * wr;
    }
#pragma unroll
    for (int off = 4; off >= 1; off >>= 1) {
        a0 += __shfl_xor(a0, off, 8);
        a1 += __shfl_xor(a1, off, 8);
    }
    if (l == 0) {
        float di = dinv[i];
        const float2 yi = *(const float2*)(y2 + i * 2);
        float x20 = (a0 + yi.x) * di + b2[0];
        float x21 = (a1 + yi.y) * di + b2[1];
        out[N_NODES + i * 2]     = x20;
        out[N_NODES + i * 2 + 1] = x21;
        float r0 = x20 > 0.0f ? x20 : 0.0f;
        float r1 = x21 > 0.0f ? x21 : 0.0f;
        float z = r0 * lin_w[0] + r1 * lin_w[1] + lin_b[0];
        out[i] = 1.0f / (1.0f + expf(-z));
    }
}

extern "C" void kernel_launch(void* const* d_in, const int* in_sizes, int n_in,
                              void* d_out, int out_size, void* d_ws, size_t ws_size,
                              hipStream_t stream) {
    const float* x     = (const float*)d_in[0];
    const int*   ei    = (const int*)d_in[1];   // [2, E] flattened
    const float* ew    = (const float*)d_in[2];
    const float* W1    = (const float*)d_in[3];
    const float* b1    = (const float*)d_in[4];
    const float* W2    = (const float*)d_in[5];
    const float* b2    = (const float*)d_in[6];
    const float* lin_w = (const float*)d_in[7];
    const float* lin_b = (const float*)d_in[8];
    float* out = (float*)d_out;

    const int* src = ei;
    const int* dst = ei + N_EDGES;

    // ---- workspace carve-up (g1/y2 alias the dead ebuf region, DISJOINTLY) ----
    char* w8 = (char*)d_ws;
    size_t off = 0;
    auto take = [&](size_t bytes) { char* p = w8 + off; off += (bytes + 15) & ~((size_t)15); return (void*)p; };
    u64*   ebuf     = (u64*)  take((size_t)N_EDGES * 8);       // 25.6 MB (dead after csr_deg_k)
    u64*   pedge    = (u64*)  take((size_t)N_EDGES * 8);       // 25.6 MB
    int*   hist_mat = (int*)  take((size_t)PART_B * NB * 4);   // ~800 KB
    int*   tot      = (int*)  take((size_t)NB * 4);
    int*   bbase    = (int*)  take((size_t)(NB + 1) * 4);
    int*   row_ptr  = (int*)  take((size_t)(N_NODES + 1) * 4);
    float* dinv     = (float*)take((size_t)N_NODES * 4);
    float* g1       = (float*)ebuf;                            // floats [0, 16N)  = 6.4 MB
    float* y2       = (float*)ebuf + (size_t)16 * N_NODES;     // floats [16N, 18N) — disjoint from g1

    const int B = 256;

    // stage 1: multisplit to 391 buckets (zero global atomics)
    hist_k<<<PART_B, B, 0, stream>>>(dst, hist_mat);
    colscan_k<<<NB, PART_B, 0, stream>>>(hist_mat, tot);
    base_k<<<1, 512, 0, stream>>>(tot, bbase);
    part_k<<<PART_B, B, 0, stream>>>(src, dst, ew, hist_mat, bbase, ebuf);

    // stage 2: per-bucket CSR + degree (zero global atomics)
    csr_deg_k<<<NB, 512, 0, stream>>>(ebuf, bbase, row_ptr, dinv, pedge);

    // layer 1 (norm algebraically folded: g1 pre-scaled by dinv[src])
    gemm1<<<(16 * N_NODES + B - 1) / B, B, 0, stream>>>(x, W1, dinv, g1);
    gather1<<<(16 * N_NODES + B - 1) / B, B, 0, stream>>>(row_ptr, pedge, dinv, g1, b1, W2, y2);

    // layer 2 + head
    gather2<<<(8 * N_NODES + B - 1) / B, B, 0, stream>>>(row_ptr, pedge, dinv, y2, b2,
                                                        lin_w, lin_b, out);
}

// Round 9
// 324.962 us; speedup vs baseline: 1.8315x; 1.0394x over previous
//
#include <hip/hip_runtime.h>
#include <math.h>

#define N_NODES 100000
#define N_EDGES 3200000
#define NPB 256                               // nodes per bucket (dst & 255, dst >> 8)
#define NB  ((N_NODES + NPB - 1) / NPB)       // 391 buckets
#define PART_B 512                            // partition blocks
#define CPB (N_EDGES / PART_B)                // 6250 edges per partition block (exact)

typedef unsigned long long u64;
typedef unsigned int u32;
typedef unsigned short u16;

// float <-> bf16 (round-to-nearest-even)
static __device__ inline u16 f2bf(float f) {
    u32 u = __float_as_uint(f);
    return (u16)((u + 0x7FFF + ((u >> 16) & 1)) >> 16);
}
static __device__ inline float bf2f(u16 h) {
    return __uint_as_float((u32)h << 16);
}

// ---------------- stage 1: multisplit into 391 buckets (NO global atomics) ----------

__global__ void hist_k(const int* __restrict__ dst, int* __restrict__ hist_mat) {
    __shared__ int h[NB];
    for (int t = threadIdx.x; t < NB; t += blockDim.x) h[t] = 0;
    __syncthreads();
    int base = blockIdx.x * CPB;
    for (int it = 0; it < (CPB + 255) / 256; it++) {
        int e = base + it * 256 + threadIdx.x;
        if (e < base + CPB) atomicAdd(&h[dst[e] >> 8], 1);   // LDS atomic only
    }
    __syncthreads();
    for (int t = threadIdx.x; t < NB; t += blockDim.x)
        hist_mat[blockIdx.x * NB + t] = h[t];
}

__global__ void colscan_k(int* __restrict__ hist_mat, int* __restrict__ tot) {
    __shared__ int s[PART_B];
    int bin = blockIdx.x, t = threadIdx.x;
    int v = hist_mat[t * NB + bin];
    s[t] = v;
    __syncthreads();
#pragma unroll
    for (int off = 1; off < PART_B; off <<= 1) {
        int u = (t >= off) ? s[t - off] : 0;
        __syncthreads();
        s[t] += u;
        __syncthreads();
    }
    hist_mat[t * NB + bin] = s[t] - v;        // exclusive within column
    if (t == PART_B - 1) tot[bin] = s[t];
}

__global__ void base_k(const int* __restrict__ tot, int* __restrict__ bbase) {
    __shared__ int s[512];
    int t = threadIdx.x;
    int v = (t < NB) ? tot[t] : 0;
    s[t] = v;
    __syncthreads();
#pragma unroll
    for (int off = 1; off < 512; off <<= 1) {
        int u = (t >= off) ? s[t - off] : 0;
        __syncthreads();
        s[t] += u;
        __syncthreads();
    }
    if (t < NB) bbase[t] = s[t] - v;
    if (t == 0) bbase[NB] = N_EDGES;
}

__global__ void part_k(const int* __restrict__ src, const int* __restrict__ dst,
                       const float* __restrict__ w, const int* __restrict__ hist_mat,
                       const int* __restrict__ bbase, u64* __restrict__ ebuf) {
    __shared__ int cur[NB];
    for (int t = threadIdx.x; t < NB; t += blockDim.x)
        cur[t] = bbase[t] + hist_mat[blockIdx.x * NB + t];
    __syncthreads();
    int base = blockIdx.x * CPB;
    for (int it = 0; it < (CPB + 255) / 256; it++) {
        int e = base + it * 256 + threadIdx.x;
        if (e < base + CPB) {
            int d = dst[e];
            int p = atomicAdd(&cur[d >> 8], 1);             // LDS atomic only
            u32 hi = ((u32)src[e] << 8) | (u32)(d & 255);
            ebuf[p] = ((u64)hi << 32) | (u64)__float_as_uint(w[e]);
        }
    }
}

// ---------------- stage 2: per-bucket CSR-ization + degree (one block per bucket) ----
__global__ void __launch_bounds__(512) csr_deg_k(
        const u64* __restrict__ ebuf, const int* __restrict__ bbase,
        int* __restrict__ row_ptr, float* __restrict__ dinv,
        u64* __restrict__ pedge) {
    __shared__ int   cnt[NPB];
    __shared__ float wsum[NPB];
    __shared__ int   sc[NPB];
    __shared__ int   cur[NPB];
    int b = blockIdx.x, t = threadIdx.x;
    if (t < NPB) { cnt[t] = 0; wsum[t] = 0.0f; }
    __syncthreads();
    int j0 = bbase[b], j1 = bbase[b + 1];
    for (int j = j0 + t; j < j1; j += 512) {
        u64 pe = ebuf[j];
        int lo = (int)((u32)(pe >> 32) & 255);
        atomicAdd(&cnt[lo], 1);                              // LDS atomic
        atomicAdd(&wsum[lo], __uint_as_float((u32)pe));      // LDS atomic
    }
    __syncthreads();
    // exclusive scan of cnt[0..255]
    int v = (t < NPB) ? cnt[t] : 0;
    if (t < NPB) sc[t] = v;
    __syncthreads();
#pragma unroll
    for (int off = 1; off < NPB; off <<= 1) {
        int u = (t < NPB && t >= off) ? sc[t - off] : 0;
        __syncthreads();
        if (t < NPB) sc[t] += u;
        __syncthreads();
    }
    int node = b * NPB + t;
    if (t < NPB) {
        int excl = sc[t] - v;
        cur[t] = j0 + excl;
        if (node < N_NODES) {
            row_ptr[node] = j0 + excl;
            dinv[node] = rsqrtf(1.0f + wsum[t]);             // self-loop weight 1
        }
    }
    if (b == NB - 1 && t == 0) row_ptr[N_NODES] = N_EDGES;
    __syncthreads();
    // pass 2: node-grouped scatter within the bucket's contiguous range
    for (int j = j0 + t; j < j1; j += 512) {
        u64 pe = ebuf[j];
        u32 hi = (u32)(pe >> 32);
        int lo = (int)(hi & 255);
        int p = atomicAdd(&cur[lo], 1);                      // LDS atomic
        pedge[p] = ((u64)(hi >> 8) << 32) | (u64)(u32)pe;    // (src, raw w)
    }
}

// ---------------- dense / gather kernels ----------------

// g1 = bf16( (x @ W1) * dinv[node] )  — 32 B/row so the table (3.2 MB) fits per-XCD L2
__global__ void gemm1(const float* __restrict__ x, const float* __restrict__ W1,
                      const float* __restrict__ dinv, u16* __restrict__ g1b) {
    __shared__ float sW[64 * 16];
    for (int t = threadIdx.x; t < 64 * 16; t += blockDim.x) sW[t] = W1[t];
    __syncthreads();
    int gid = blockIdx.x * blockDim.x + threadIdx.x;
    int node = gid >> 4, c = gid & 15;
    if (node >= N_NODES) return;
    const float* xr = x + node * 64;
    float acc = 0.0f;
#pragma unroll
    for (int k = 0; k < 64; k++) acc += xr[k] * sW[k * 16 + c];
    g1b[node * 16 + c] = f2bf(acc * dinv[node]);
}

// conv1 gather (bf16 table, fp32 accum) + bias + relu, fused gemm2 -> y2 = x2pre*dinv
__global__ void gather1(const int* __restrict__ row_ptr, const u64* __restrict__ pedge,
                        const float* __restrict__ dinv, const u16* __restrict__ g1b,
                        const float* __restrict__ b1, const float* __restrict__ W2,
                        float* __restrict__ y2) {
    int gid = blockIdx.x * blockDim.x + threadIdx.x;
    int node = gid >> 4, c = gid & 15;
    if (node >= N_NODES) return;
    float acc = bf2f(g1b[node * 16 + c]);              // self-loop (g1 = h1*dinv)
    int j0 = row_ptr[node], j1 = row_ptr[node + 1];
    for (int j = j0; j < j1; j++) {
        u64 pe = pedge[j];
        int s = (int)(pe >> 32);
        float wr = __uint_as_float((unsigned)pe);
        acc += bf2f(g1b[s * 16 + c]) * wr;
    }
    float di = dinv[node];
    float v = acc * di + b1[c];
    v = v > 0.0f ? v : 0.0f;                           // h2, in-register
    // fused gemm2: x2pre[node][k] = sum_c v_c * W2[c][k]
    float p0 = v * W2[c * 2];
    float p1 = v * W2[c * 2 + 1];
#pragma unroll
    for (int off = 8; off >= 1; off >>= 1) {
        p0 += __shfl_xor(p0, off, 16);
        p1 += __shfl_xor(p1, off, 16);
    }
    if (c == 0) {
        y2[node * 2]     = p0 * di;                    // pre-scale for layer 2
        y2[node * 2 + 1] = p1 * di;
    }
}

// conv2 gather (8 lanes/node) + bias + relu + sigmoid head
__global__ void gather2(const int* __restrict__ row_ptr, const u64* __restrict__ pedge,
                        const float* __restrict__ dinv, const float* __restrict__ y2,
                        const float* __restrict__ b2, const float* __restrict__ lin_w,
                        const float* __restrict__ lin_b, float* __restrict__ out) {
    int gid = blockIdx.x * blockDim.x + threadIdx.x;
    int i = gid >> 3, l = gid & 7;
    if (i >= N_NODES) return;
    int j0 = row_ptr[i], j1 = row_ptr[i + 1];
    float a0 = 0.0f, a1 = 0.0f;
    for (int j = j0 + l; j < j1; j += 8) {
        u64 pe = pedge[j];
        int s = (int)(pe >> 32);
        float wr = __uint_as_float((unsigned)pe);
        const float2 ys = *(const float2*)(y2 + s * 2);
        a0 += ys.x * wr;
        a1 += ys.y * wr;
    }
#pragma unroll
    for (int off = 4; off >= 1; off >>= 1) {
        a0 += __shfl_xor(a0, off, 8);
        a1 += __shfl_xor(a1, off, 8);
    }
    if (l == 0) {
        float di = dinv[i];
        const float2 yi = *(const float2*)(y2 + i * 2);
        float x20 = (a0 + yi.x) * di + b2[0];
        float x21 = (a1 + yi.y) * di + b2[1];
        out[N_NODES + i * 2]     = x20;
        out[N_NODES + i * 2 + 1] = x21;
        float r0 = x20 > 0.0f ? x20 : 0.0f;
        float r1 = x21 > 0.0f ? x21 : 0.0f;
        float z = r0 * lin_w[0] + r1 * lin_w[1] + lin_b[0];
        out[i] = 1.0f / (1.0f + expf(-z));
    }
}

extern "C" void kernel_launch(void* const* d_in, const int* in_sizes, int n_in,
                              void* d_out, int out_size, void* d_ws, size_t ws_size,
                              hipStream_t stream) {
    const float* x     = (const float*)d_in[0];
    const int*   ei    = (const int*)d_in[1];   // [2, E] flattened
    const float* ew    = (const float*)d_in[2];
    const float* W1    = (const float*)d_in[3];
    const float* b1    = (const float*)d_in[4];
    const float* W2    = (const float*)d_in[5];
    const float* b2    = (const float*)d_in[6];
    const float* lin_w = (const float*)d_in[7];
    const float* lin_b = (const float*)d_in[8];
    float* out = (float*)d_out;

    const int* src = ei;
    const int* dst = ei + N_EDGES;

    // ---- workspace carve-up (g1b/y2 alias the dead ebuf region, DISJOINTLY) ----
    char* w8 = (char*)d_ws;
    size_t off = 0;
    auto take = [&](size_t bytes) { char* p = w8 + off; off += (bytes + 15) & ~((size_t)15); return (void*)p; };
    u64*   ebuf     = (u64*)  take((size_t)N_EDGES * 8);       // 25.6 MB (dead after csr_deg_k)
    u64*   pedge    = (u64*)  take((size_t)N_EDGES * 8);       // 25.6 MB
    int*   hist_mat = (int*)  take((size_t)PART_B * NB * 4);   // ~800 KB
    int*   tot      = (int*)  take((size_t)NB * 4);
    int*   bbase    = (int*)  take((size_t)(NB + 1) * 4);
    int*   row_ptr  = (int*)  take((size_t)(N_NODES + 1) * 4);
    float* dinv     = (float*)take((size_t)N_NODES * 4);
    u16*   g1b      = (u16*)ebuf;                              // bytes [0, 3.2MB)
    float* y2       = (float*)ebuf + (size_t)8 * N_NODES;      // bytes [3.2MB, 4.0MB) — disjoint

    const int B = 256;

    // stage 1: multisplit to 391 buckets (zero global atomics)
    hist_k<<<PART_B, B, 0, stream>>>(dst, hist_mat);
    colscan_k<<<NB, PART_B, 0, stream>>>(hist_mat, tot);
    base_k<<<1, 512, 0, stream>>>(tot, bbase);
    part_k<<<PART_B, B, 0, stream>>>(src, dst, ew, hist_mat, bbase, ebuf);

    // stage 2: per-bucket CSR + degree (zero global atomics)
    csr_deg_k<<<NB, 512, 0, stream>>>(ebuf, bbase, row_ptr, dinv, pedge);

    // layer 1 (norm algebraically folded: g1 pre-scaled by dinv[src]; bf16 table)
    gemm1<<<(16 * N_NODES + B - 1) / B, B, 0, stream>>>(x, W1, dinv, g1b);
    gather1<<<(16 * N_NODES + B - 1) / B, B, 0, stream>>>(row_ptr, pedge, dinv, g1b, b1, W2, y2);

    // layer 2 + head
    gather2<<<(8 * N_NODES + B - 1) / B, B, 0, stream>>>(row_ptr, pedge, dinv, y2, b2,
                                                        lin_w, lin_b, out);
}

// Round 10
// 321.390 us; speedup vs baseline: 1.8518x; 1.0111x over previous
//
#include <hip/hip_runtime.h>
#include <math.h>

#define N_NODES 100000
#define N_EDGES 3200000
#define LO_BITS 7
#define NPB 128                               // nodes per bucket (dst & 127, dst >> 7)
#define NB  ((N_NODES + NPB - 1) / NPB)       // 782 buckets
#define PART_B 512                            // partition blocks
#define CPB (N_EDGES / PART_B)                // 6250 edges per partition block (exact)

typedef unsigned long long u64;
typedef unsigned int u32;
typedef unsigned short u16;

// float <-> bf16 (round-to-nearest-even)
static __device__ inline u16 f2bf(float f) {
    u32 u = __float_as_uint(f);
    return (u16)((u + 0x7FFF + ((u >> 16) & 1)) >> 16);
}
static __device__ inline float bf2f(u16 h) {
    return __uint_as_float((u32)h << 16);
}

// ---------------- stage 1: multisplit into 782 buckets (NO global atomics) ----------

__global__ void hist_k(const int* __restrict__ dst, int* __restrict__ hist_mat) {
    __shared__ int h[NB];
    for (int t = threadIdx.x; t < NB; t += blockDim.x) h[t] = 0;
    __syncthreads();
    int base = blockIdx.x * CPB;
    for (int it = 0; it < (CPB + 255) / 256; it++) {
        int e = base + it * 256 + threadIdx.x;
        if (e < base + CPB) atomicAdd(&h[dst[e] >> LO_BITS], 1);   // LDS atomic only
    }
    __syncthreads();
    for (int t = threadIdx.x; t < NB; t += blockDim.x)
        hist_mat[blockIdx.x * NB + t] = h[t];
}

__global__ void colscan_k(int* __restrict__ hist_mat, int* __restrict__ tot) {
    __shared__ int s[PART_B];
    int bin = blockIdx.x, t = threadIdx.x;
    int v = hist_mat[t * NB + bin];
    s[t] = v;
    __syncthreads();
#pragma unroll
    for (int off = 1; off < PART_B; off <<= 1) {
        int u = (t >= off) ? s[t - off] : 0;
        __syncthreads();
        s[t] += u;
        __syncthreads();
    }
    hist_mat[t * NB + bin] = s[t] - v;        // exclusive within column
    if (t == PART_B - 1) tot[bin] = s[t];
}

__global__ void base_k(const int* __restrict__ tot, int* __restrict__ bbase) {
    __shared__ int s[1024];
    int t = threadIdx.x;
    int v = (t < NB) ? tot[t] : 0;
    s[t] = v;
    __syncthreads();
#pragma unroll
    for (int off = 1; off < 1024; off <<= 1) {
        int u = (t >= off) ? s[t - off] : 0;
        __syncthreads();
        s[t] += u;
        __syncthreads();
    }
    if (t < NB) bbase[t] = s[t] - v;
    if (t == 0) bbase[NB] = N_EDGES;
}

__global__ void part_k(const int* __restrict__ src, const int* __restrict__ dst,
                       const float* __restrict__ w, const int* __restrict__ hist_mat,
                       const int* __restrict__ bbase, u64* __restrict__ ebuf) {
    __shared__ int cur[NB];
    for (int t = threadIdx.x; t < NB; t += blockDim.x)
        cur[t] = bbase[t] + hist_mat[blockIdx.x * NB + t];
    __syncthreads();
    int base = blockIdx.x * CPB;
    for (int it = 0; it < (CPB + 255) / 256; it++) {
        int e = base + it * 256 + threadIdx.x;
        if (e < base + CPB) {
            int d = dst[e];
            int p = atomicAdd(&cur[d >> LO_BITS], 1);       // LDS atomic only
            u32 hi = ((u32)src[e] << LO_BITS) | (u32)(d & (NPB - 1));
            ebuf[p] = ((u64)hi << 32) | (u64)__float_as_uint(w[e]);
        }
    }
}

// ---------------- stage 2: per-bucket CSR-ization + degree (one block per bucket) ----
__global__ void __launch_bounds__(512) csr_deg_k(
        const u64* __restrict__ ebuf, const int* __restrict__ bbase,
        int* __restrict__ row_ptr, float* __restrict__ dinv,
        u64* __restrict__ pedge) {
    __shared__ int   cnt[NPB];
    __shared__ float wsum[NPB];
    __shared__ int   sc[NPB];
    __shared__ int   cur[NPB];
    int b = blockIdx.x, t = threadIdx.x;
    if (t < NPB) { cnt[t] = 0; wsum[t] = 0.0f; }
    __syncthreads();
    int j0 = bbase[b], j1 = bbase[b + 1];
    for (int j = j0 + t; j < j1; j += 512) {
        u64 pe = ebuf[j];
        int lo = (int)((u32)(pe >> 32) & (NPB - 1));
        atomicAdd(&cnt[lo], 1);                              // LDS atomic
        atomicAdd(&wsum[lo], __uint_as_float((u32)pe));      // LDS atomic
    }
    __syncthreads();
    // exclusive scan of cnt[0..NPB)
    int v = (t < NPB) ? cnt[t] : 0;
    if (t < NPB) sc[t] = v;
    __syncthreads();
#pragma unroll
    for (int off = 1; off < NPB; off <<= 1) {
        int u = (t < NPB && t >= off) ? sc[t - off] : 0;
        __syncthreads();
        if (t < NPB) sc[t] += u;
        __syncthreads();
    }
    int node = b * NPB + t;
    if (t < NPB) {
        int excl = sc[t] - v;
        cur[t] = j0 + excl;
        if (node < N_NODES) {
            row_ptr[node] = j0 + excl;
            dinv[node] = rsqrtf(1.0f + wsum[t]);             // self-loop weight 1
        }
    }
    if (b == NB - 1 && t == 0) row_ptr[N_NODES] = N_EDGES;
    __syncthreads();
    // pass 2: node-grouped scatter within the bucket's contiguous range (L2-hot)
    for (int j = j0 + t; j < j1; j += 512) {
        u64 pe = ebuf[j];
        u32 hi = (u32)(pe >> 32);
        int lo = (int)(hi & (NPB - 1));
        int p = atomicAdd(&cur[lo], 1);                      // LDS atomic
        pedge[p] = ((u64)(hi >> LO_BITS) << 32) | (u64)(u32)pe;   // (src, raw w)
    }
}

// ---------------- dense / gather kernels ----------------

// g1 = bf16( (x @ W1) * dinv[node] )  — 3.2 MB table fits per-XCD L2
__global__ void gemm1(const float* __restrict__ x, const float* __restrict__ W1,
                      const float* __restrict__ dinv, u16* __restrict__ g1b) {
    __shared__ float sW[64 * 16];
    for (int t = threadIdx.x; t < 64 * 16; t += blockDim.x) sW[t] = W1[t];
    __syncthreads();
    int gid = blockIdx.x * blockDim.x + threadIdx.x;
    int node = gid >> 4, c = gid & 15;
    if (node >= N_NODES) return;
    const float* xr = x + node * 64;
    float acc = 0.0f;
#pragma unroll
    for (int k = 0; k < 64; k++) acc += xr[k] * sW[k * 16 + c];
    g1b[node * 16 + c] = f2bf(acc * dinv[node]);
}

// conv1 gather: 64 lanes/node = 4 edge-groups x 16 feats; fp32 accum;
// shuffle-reduce over edge-groups, relu, then over feats for fused gemm2.
__global__ void gather1(const int* __restrict__ row_ptr, const u64* __restrict__ pedge,
                        const float* __restrict__ dinv, const u16* __restrict__ g1b,
                        const float* __restrict__ b1, const float* __restrict__ W2,
                        float* __restrict__ y2) {
    int gid = blockIdx.x * blockDim.x + threadIdx.x;
    int node = gid >> 6;
    int c  = gid & 15;          // feature lane
    int eg = (gid >> 4) & 3;    // edge group
    if (node >= N_NODES) return;
    float acc = (eg == 0) ? bf2f(g1b[node * 16 + c]) : 0.0f;   // self-loop once
    int j0 = row_ptr[node], j1 = row_ptr[node + 1];
    for (int j = j0 + eg; j < j1; j += 4) {
        u64 pe = pedge[j];
        int s = (int)(pe >> 32);
        float wr = __uint_as_float((unsigned)pe);
        acc += bf2f(g1b[s * 16 + c]) * wr;
    }
    // reduce across the 4 edge groups (lanes c+16*eg within the 64-lane wave)
    acc += __shfl_xor(acc, 16, 64);
    acc += __shfl_xor(acc, 32, 64);
    float di = dinv[node];
    float v = acc * di + b1[c];
    v = v > 0.0f ? v : 0.0f;                           // h2, in-register
    // fused gemm2 over the 16 feature lanes
    float p0 = v * W2[c * 2];
    float p1 = v * W2[c * 2 + 1];
#pragma unroll
    for (int off = 8; off >= 1; off >>= 1) {
        p0 += __shfl_xor(p0, off, 16);
        p1 += __shfl_xor(p1, off, 16);
    }
    if (c == 0 && eg == 0) {
        y2[node * 2]     = p0 * di;                    // pre-scale for layer 2
        y2[node * 2 + 1] = p1 * di;
    }
}

// conv2 gather: 16 lanes/node = 8 edge-lanes x 2 components
__global__ void gather2(const int* __restrict__ row_ptr, const u64* __restrict__ pedge,
                        const float* __restrict__ dinv, const float* __restrict__ y2,
                        const float* __restrict__ b2, const float* __restrict__ lin_w,
                        const float* __restrict__ lin_b, float* __restrict__ out) {
    int gid = blockIdx.x * blockDim.x + threadIdx.x;
    int i  = gid >> 4;
    int k  = gid & 1;           // component
    int el = (gid >> 1) & 7;    // edge lane
    if (i >= N_NODES) return;
    int j0 = row_ptr[i], j1 = row_ptr[i + 1];
    float a = 0.0f;
    for (int j = j0 + el; j < j1; j += 8) {
        u64 pe = pedge[j];
        int s = (int)(pe >> 32);
        float wr = __uint_as_float((unsigned)pe);
        a += y2[s * 2 + k] * wr;
    }
    // reduce across the 8 edge lanes (stride-2 lanes within 16)
#pragma unroll
    for (int off = 2; off <= 8; off <<= 1) a += __shfl_xor(a, off, 16);
    float a_other = __shfl_xor(a, 1, 16);              // the other component's sum
    if (k == 0 && el == 0) {
        float a0 = a, a1 = a_other;
        float di = dinv[i];
        const float2 yi = *(const float2*)(y2 + i * 2);
        float x20 = (a0 + yi.x) * di + b2[0];
        float x21 = (a1 + yi.y) * di + b2[1];
        out[N_NODES + i * 2]     = x20;
        out[N_NODES + i * 2 + 1] = x21;
        float r0 = x20 > 0.0f ? x20 : 0.0f;
        float r1 = x21 > 0.0f ? x21 : 0.0f;
        float z = r0 * lin_w[0] + r1 * lin_w[1] + lin_b[0];
        out[i] = 1.0f / (1.0f + expf(-z));
    }
}

extern "C" void kernel_launch(void* const* d_in, const int* in_sizes, int n_in,
                              void* d_out, int out_size, void* d_ws, size_t ws_size,
                              hipStream_t stream) {
    const float* x     = (const float*)d_in[0];
    const int*   ei    = (const int*)d_in[1];   // [2, E] flattened
    const float* ew    = (const float*)d_in[2];
    const float* W1    = (const float*)d_in[3];
    const float* b1    = (const float*)d_in[4];
    const float* W2    = (const float*)d_in[5];
    const float* b2    = (const float*)d_in[6];
    const float* lin_w = (const float*)d_in[7];
    const float* lin_b = (const float*)d_in[8];
    float* out = (float*)d_out;

    const int* src = ei;
    const int* dst = ei + N_EDGES;

    // ---- workspace carve-up (g1b/y2 alias the dead ebuf region, DISJOINTLY) ----
    char* w8 = (char*)d_ws;
    size_t off = 0;
    auto take = [&](size_t bytes) { char* p = w8 + off; off += (bytes + 15) & ~((size_t)15); return (void*)p; };
    u64*   ebuf     = (u64*)  take((size_t)N_EDGES * 8);       // 25.6 MB (dead after csr_deg_k)
    u64*   pedge    = (u64*)  take((size_t)N_EDGES * 8);       // 25.6 MB
    int*   hist_mat = (int*)  take((size_t)PART_B * NB * 4);   // ~1.6 MB
    int*   tot      = (int*)  take((size_t)NB * 4);
    int*   bbase    = (int*)  take((size_t)(NB + 1) * 4);
    int*   row_ptr  = (int*)  take((size_t)(N_NODES + 1) * 4);
    float* dinv     = (float*)take((size_t)N_NODES * 4);
    u16*   g1b      = (u16*)ebuf;                              // bytes [0, 3.2MB)
    float* y2       = (float*)ebuf + (size_t)8 * N_NODES;      // bytes [3.2MB, 4.0MB)

    const int B = 256;

    // stage 1: multisplit to 782 buckets (zero global atomics)
    hist_k<<<PART_B, B, 0, stream>>>(dst, hist_mat);
    colscan_k<<<NB, PART_B, 0, stream>>>(hist_mat, tot);
    base_k<<<1, 1024, 0, stream>>>(tot, bbase);
    part_k<<<PART_B, B, 0, stream>>>(src, dst, ew, hist_mat, bbase, ebuf);

    // stage 2: per-bucket CSR + degree (zero global atomics)
    csr_deg_k<<<NB, 512, 0, stream>>>(ebuf, bbase, row_ptr, dinv, pedge);

    // layer 1 (norm algebraically folded: g1 pre-scaled by dinv[src]; bf16 table)
    gemm1<<<(16 * N_NODES + B - 1) / B, B, 0, stream>>>(x, W1, dinv, g1b);
    gather1<<<(64 * N_NODES + B - 1) / B, B, 0, stream>>>(row_ptr, pedge, dinv, g1b, b1, W2, y2);

    // layer 2 + head
    gather2<<<(16 * N_NODES + B - 1) / B, B, 0, stream>>>(row_ptr, pedge, dinv, y2, b2,
                                                         lin_w, lin_b, out);
}